// Round 5
// baseline (368.107 us; speedup 1.0000x reference)
//
#include <hip/hip_runtime.h>
#include <math.h>

#define B_     64
#define S_     4096
#define H_     256
#define SPLIT  128
#define ROWS   (S_ / SPLIT)        // 32 rows (positions) staged per block
#define RPAD   260                 // padded LDS row stride in floats (1024 B + 16 B pad)
#define RECS   264                 // ws record stride in floats: v[256], M, l, pad

// Pass 1: stage a 32-position chunk (32 KiB, contiguous in enc) into LDS with
// coalesced float4 loads, then exact two-pass softmax + weighted sum from LDS.
// enc is read exactly once from HBM.
__global__ __launch_bounds__(256) void attn_pass1(
    const float* __restrict__ hidden,   // (B, H)
    const float* __restrict__ enc,      // (B, S, H)
    float* __restrict__ ws)             // (B*SPLIT) records of RECS floats
{
    const int split = blockIdx.x;
    const int b     = blockIdx.y;
    const int tid   = threadIdx.x;
    const int wave  = tid >> 6;
    const int lane  = tid & 63;
    const int g     = lane >> 4;        // row-within-round (energy pass)
    const int i     = lane & 15;        // H-slice index (energy pass)

    __shared__ float tile[ROWS * RPAD];   // 33280 B
    __shared__ float s_e[ROWS];           // energies -> weights (in place)
    __shared__ float s_M;
    __shared__ float s_lsum;

    // ---- stage: 8 independent float4 loads per lane, all issued up front ----
    const float4* gsrc = (const float4*)(enc + ((size_t)b * S_ + (size_t)split * ROWS) * H_);
    float4 stg[8];
    #pragma unroll
    for (int j = 0; j < 8; ++j) stg[j] = gsrc[tid + 256 * j];

    // h fragments for the energy pass (in flight alongside the stage loads)
    const float4* hrow = (const float4*)(hidden + (size_t)b * H_);
    float4 h4[4];
    #pragma unroll
    for (int k = 0; k < 4; ++k) h4[k] = hrow[i + 16 * k];

    // f = tid + 256j  ->  row = wave + 4j, col4 = lane: each wave-store fills one
    // whole 1 KiB row (pad never a store target, contiguous -> conflict-free).
    #pragma unroll
    for (int j = 0; j < 8; ++j) {
        const int row = wave + 4 * j;
        ((float4*)&tile[row * RPAD])[lane] = stg[j];
    }
    __syncthreads();

    // ---- energy pass: 16-lane group g handles row wave*8 + t*4 + g ----
    #pragma unroll
    for (int t = 0; t < 2; ++t) {
        const int r = wave * (ROWS / 4) + t * 4 + g;
        const float4* row = (const float4*)&tile[r * RPAD];
        float e = 0.f;
        #pragma unroll
        for (int k = 0; k < 4; ++k) {
            const float4 v = row[i + 16 * k];
            e = fmaf(v.x, h4[k].x, e);
            e = fmaf(v.y, h4[k].y, e);
            e = fmaf(v.z, h4[k].z, e);
            e = fmaf(v.w, h4[k].w, e);
        }
        e += __shfl_xor(e, 1);
        e += __shfl_xor(e, 2);
        e += __shfl_xor(e, 4);
        e += __shfl_xor(e, 8);
        if (i == 0) s_e[r] = e;
    }
    __syncthreads();

    // ---- wave 0: block max, convert energies -> weights, sum of weights ----
    if (wave == 0) {
        const float x = (lane < ROWS) ? s_e[lane] : -INFINITY;
        float mx = x;
        mx = fmaxf(mx, __shfl_xor(mx, 1));
        mx = fmaxf(mx, __shfl_xor(mx, 2));
        mx = fmaxf(mx, __shfl_xor(mx, 4));
        mx = fmaxf(mx, __shfl_xor(mx, 8));
        mx = fmaxf(mx, __shfl_xor(mx, 16));   // lanes 0..31 now hold M
        const float w = (lane < ROWS) ? __expf(x - mx) : 0.f;
        if (lane < ROWS) s_e[lane] = w;
        float ls = w;
        ls += __shfl_xor(ls, 1);
        ls += __shfl_xor(ls, 2);
        ls += __shfl_xor(ls, 4);
        ls += __shfl_xor(ls, 8);
        ls += __shfl_xor(ls, 16);
        ls += __shfl_xor(ls, 32);
        if (lane == 0) { s_M = mx; s_lsum = ls; }
    }
    __syncthreads();

    // ---- weight pass: thread tid owns h-index tid over ALL 32 rows ----
    float ctx = 0.f;
    #pragma unroll
    for (int r = 0; r < ROWS; ++r)
        ctx = fmaf(s_e[r], tile[r * RPAD + tid], ctx);   // s_e[r]: broadcast read

    float* rec = ws + (size_t)(b * SPLIT + split) * RECS;
    rec[tid] = ctx;
    if (tid == 0) { rec[256] = s_M; rec[257] = s_lsum; }
}

// Pass 2: merge SPLIT partials per batch, normalize, write context.
__global__ __launch_bounds__(256) void attn_pass2(
    const float* __restrict__ ws,
    float* __restrict__ out)            // (B, H)
{
    const int b   = blockIdx.x;
    const int tid = threadIdx.x;

    __shared__ float s_m[SPLIT], s_l2[SPLIT];
    if (tid < SPLIT) {
        const float* rec = ws + (size_t)(b * SPLIT + tid) * RECS;
        s_m[tid]  = rec[256];
        s_l2[tid] = rec[257];
    }
    __syncthreads();

    float M = -INFINITY;
    #pragma unroll 16
    for (int i = 0; i < SPLIT; ++i) M = fmaxf(M, s_m[i]);

    float denom = 0.f, v = 0.f;
    #pragma unroll 16
    for (int i = 0; i < SPLIT; ++i) {
        const float f = __expf(s_m[i] - M);
        denom = fmaf(f, s_l2[i], denom);
        v     = fmaf(f, ws[(size_t)(b * SPLIT + i) * RECS + tid], v);
    }
    out[(size_t)b * H_ + tid] = v / denom;
}

extern "C" void kernel_launch(void* const* d_in, const int* in_sizes, int n_in,
                              void* d_out, int out_size, void* d_ws, size_t ws_size,
                              hipStream_t stream) {
    const float* hidden = (const float*)d_in[0];   // (1, B, H) fp32
    const float* enc    = (const float*)d_in[1];   // (B, S, H) fp32
    float* out = (float*)d_out;                    // (B, H) fp32
    float* ws  = (float*)d_ws;                     // uses ~8.7 MB

    attn_pass1<<<dim3(SPLIT, B_), 256, 0, stream>>>(hidden, enc, ws);
    attn_pass2<<<B_, 256, 0, stream>>>(ws, out);
}